// Round 8
// baseline (236.227 us; speedup 1.0000x reference)
//
#include <hip/hip_runtime.h>
#include <hip/hip_bf16.h>

#define NS_    48
#define NV_    10
#define N_NODE 20000
#define N_EDGE 100000
#define HID    144     // 3*NS
#define OUTC   58      // 48 + 10
#define ODIM   78      // 48 + 30
#define TILE   64
#define NTILES 1563    // ceil(100000/64)
#define TEB    128     // kernel-B edges per block
#define NB2    782     // ceil(100000/128)
#define LDE    160     // padded K (144->160), LDS row stride (bf16 elems)
#define WNUM   2784

typedef __attribute__((ext_vector_type(8))) short bf8;
typedef __attribute__((ext_vector_type(4))) float f32x4;

__device__ __forceinline__ short f2bf(float x) {
  __hip_bfloat16 h = __float2bfloat16(x);
  union { __hip_bfloat16 b; short s; } u; u.b = h; return u.s;
}
__device__ __forceinline__ unsigned pk2(float a, float b) {
  return (unsigned)(unsigned short)f2bf(a) | ((unsigned)(unsigned short)f2bf(b) << 16);
}

// ---------------- prep: pack B operands into MFMA fragment order ----------------
__global__ void prep_fc1(const float* __restrict__ w, short* __restrict__ dst) {
  int idx = blockIdx.x * 256 + threadIdx.x;
  if (idx >= 9 * 5 * 512) return;
  int j = idx & 7, l = (idx >> 3) & 63, t = idx >> 9;
  int ks = t % 5, nt = t / 5;
  int k = ks * 32 + ((l >> 4) << 3) + j;
  int n = nt * 16 + (l & 15);
  dst[idx] = f2bf(k < HID ? w[k * HID + n] : 0.f);
}

// G frags: [i 48][strip 4][ks 5][lane][j]; row k==144 carries fc2_b (pairs with H col144==1)
__global__ void prep_g(const float* __restrict__ w, const float* __restrict__ b,
                       short* __restrict__ dst) {
  int idx = blockIdx.x * 256 + threadIdx.x;
  if (idx >= 48 * 4 * 5 * 512) return;
  int j = idx & 7, l = (idx >> 3) & 63, t = idx >> 9;
  int ks = t % 5, u = t / 5;
  int strip = u & 3, i = u >> 2;
  int k = ks * 32 + ((l >> 4) << 3) + j;
  int c = strip * 16 + (l & 15);
  float v = 0.f;
  if (c < OUTC) {
    if (k < HID)
      v = (c < NS_) ? w[k * WNUM + i * NS_ + c]
                    : w[k * WNUM + NS_ * NS_ + i * NV_ + (c - NS_)];
    else if (k == HID)
      v = (c < NS_) ? b[i * NS_ + c]
                    : b[NS_ * NS_ + i * NV_ + (c - NS_)];
  }
  dst[idx] = f2bf(v);
}

// ---------------- CSR build: counting sort of edges by src ----------------
__global__ void k_hist(const int* __restrict__ eidx, int* __restrict__ cnt) {
  int e = blockIdx.x * 256 + threadIdx.x;
  if (e < N_EDGE) atomicAdd(&cnt[eidx[e]], 1);
}

__global__ void k_scan1(const int* __restrict__ cnt, int* __restrict__ locexc,
                        int* __restrict__ blksum) {
  __shared__ int sh[256];
  int g = blockIdx.x * 256 + threadIdx.x;
  int v = (g < N_NODE) ? cnt[g] : 0;
  sh[threadIdx.x] = v;
  __syncthreads();
  for (int d = 1; d < 256; d <<= 1) {
    int t = (threadIdx.x >= d) ? sh[threadIdx.x - d] : 0;
    __syncthreads();
    sh[threadIdx.x] += t;
    __syncthreads();
  }
  if (g < N_NODE) locexc[g] = sh[threadIdx.x] - v;
  if (threadIdx.x == 255) blksum[blockIdx.x] = sh[255];
}

__global__ void k_scan2(const int* __restrict__ blksum, int* __restrict__ blkoff) {
  __shared__ int sh[128];
  int t = threadIdx.x;
  int v = (t < 79) ? blksum[t] : 0;
  sh[t] = v;
  __syncthreads();
  for (int d = 1; d < 128; d <<= 1) {
    int x = (t >= d) ? sh[t - d] : 0;
    __syncthreads();
    sh[t] += x;
    __syncthreads();
  }
  if (t < 79) blkoff[t] = sh[t] - v;
}

__global__ void k_scatter(const int* __restrict__ eidx, const int* __restrict__ locexc,
                          const int* __restrict__ blkoff, int* __restrict__ cursor,
                          int* __restrict__ sortedE) {
  int e = blockIdx.x * 256 + threadIdx.x;
  if (e >= N_EDGE) return;
  int s = eidx[e];
  int base = blkoff[s >> 8] + locexc[s];
  int r = atomicAdd(&cursor[s], 1);
  sortedE[base + r] = e;
}

// ================= kernel A — gather + fc1, frag-order export =================
__global__ __launch_bounds__(256) void gather_fc1(
    const float* __restrict__ node_attr, const int* __restrict__ eidx,
    const float* __restrict__ edge_attr, const float* __restrict__ edge_sh,
    const float* __restrict__ fc1_b, const int* __restrict__ sortedE,
    const short* __restrict__ fc1frag,
    short* __restrict__ Hg, float* __restrict__ xTg,
    float* __restrict__ shsg, int* __restrict__ srcsg)
{
  __shared__ short EA[TILE * LDE];   // ea tile -> H tile (in place)

  const int tid  = threadIdx.x;
  const int lane = tid & 63;
  const int wv   = tid >> 6;
  const size_t tile = blockIdx.x;
  const int base = (int)tile * TILE;

  // zero K-pad cols 144..159
  for (int t = tid; t < TILE * 16; t += 256) {
    int r = t >> 4, c = t & 15;
    EA[r * LDE + HID + c] = 0;
  }

  // ---- gather (src-sorted edge ids): 4 threads per edge, 12 cols each ----
  {
    const int el = tid >> 2, part = tid & 3;
    const int gi = base + el;
    const bool ev = gi < N_EDGE;
    const int e  = ev ? sortedE[gi] : 0;
    const int es = ev ? eidx[e] : 0;
    const int ed = ev ? eidx[N_EDGE + e] : 0;
    if (part == 0) {
      srcsg[tile * TILE + el] = ev ? es : -1;
      #pragma unroll
      for (int c = 0; c < 4; ++c)
        shsg[tile * 256 + el * 4 + c] = ev ? edge_sh[(size_t)e * 9 + c] : 0.f;
    }
    const float4* pa = (const float4*)(edge_attr + (size_t)e * NS_);
    const float4* ps = (const float4*)(node_attr + (size_t)es * NS_);
    const float4* pd = (const float4*)(node_attr + (size_t)ed * NS_);
    const float4 z4 = make_float4(0.f, 0.f, 0.f, 0.f);
    #pragma unroll
    for (int q = 0; q < 3; ++q) {
      const int c0 = part * 12 + q * 4;
      float4 va = ev ? pa[part * 3 + q] : z4;
      float4 vs = ev ? ps[part * 3 + q] : z4;
      float4 vd = ev ? pd[part * 3 + q] : z4;
      *(uint2*)&EA[el * LDE + c0]           = make_uint2(pk2(va.x, va.y), pk2(va.z, va.w));
      *(uint2*)&EA[el * LDE + NS_ + c0]     = make_uint2(pk2(vs.x, vs.y), pk2(vs.z, vs.w));
      *(uint2*)&EA[el * LDE + 2 * NS_ + c0] = make_uint2(pk2(vd.x, vd.y), pk2(vd.z, vd.w));
      xTg[tile * 3072 + (size_t)(c0 + 0) * TILE + el] = vd.x;
      xTg[tile * 3072 + (size_t)(c0 + 1) * TILE + el] = vd.y;
      xTg[tile * 3072 + (size_t)(c0 + 2) * TILE + el] = vd.z;
      xTg[tile * 3072 + (size_t)(c0 + 3) * TILE + el] = vd.w;
    }
  }
  __syncthreads();

  // ---- fc1: wave wv computes H rows [wv*16, wv*16+16); H overwrites EA in place ----
  {
    const int mrow = lane & 15;
    const int koff = (lane >> 4) << 3;
    bf8 aF[5];
    #pragma unroll
    for (int ks = 0; ks < 5; ++ks)
      aF[ks] = *(const bf8*)&EA[(wv * 16 + mrow) * LDE + ks * 32 + koff];
    #pragma unroll
    for (int nt = 0; nt < 9; ++nt) {
      f32x4 acc = {0.f, 0.f, 0.f, 0.f};
      #pragma unroll
      for (int ks = 0; ks < 5; ++ks) {
        bf8 bF = *(const bf8*)&fc1frag[((nt * 5 + ks) * 64 + lane) * 8];
        acc = __builtin_amdgcn_mfma_f32_16x16x32_bf16(aF[ks], bF, acc, 0, 0, 0);
      }
      const int col = nt * 16 + mrow;
      const float bb = fc1_b[col];
      #pragma unroll
      for (int r = 0; r < 4; ++r) {
        float h = acc[r] + bb;
        h = h > 0.f ? h : 0.f;
        EA[(wv * 16 + ((lane >> 4) << 2) + r) * LDE + col] = f2bf(h);
      }
    }
    if (lane < 16) EA[(wv * 16 + lane) * LDE + HID] = (short)0x3F80;  // 1.0 col for bias

    // frag-order export of this wave's 16 rows
    #pragma unroll
    for (int ks = 0; ks < 5; ++ks) {
      bf8 v = *(const bf8*)&EA[(wv * 16 + mrow) * LDE + ks * 32 + koff];
      *(bf8*)&Hg[tile * 10240 + (size_t)(wv * 5 + ks) * 512 + lane * 8] = v;
    }
  }
}

// ========== kernel B — 128 edges/block, 16 waves = 4 col-strips x 4 edge-quarters ==========
__global__ __launch_bounds__(1024) void tp_scatter(
    const short* __restrict__ gfrag, const short* __restrict__ Hg,
    const float* __restrict__ xTg, const float* __restrict__ shsg,
    const int* __restrict__ srcsg, float* __restrict__ out)
{
  __shared__ float UN[TEB * 80];     // xT [48][128] during loop; O [128][80] after
  __shared__ float shsS[TEB * 4];
  __shared__ int   srcsS[TEB];
  __shared__ int   runStart[TEB + 1], runSrc[TEB];
  __shared__ unsigned long long hmaskSh[2], vmaskSh[2];
  __shared__ int   nRunsSh;

  const int tid   = threadIdx.x;
  const int lane  = tid & 63;
  const int wv    = tid >> 6;        // 0..15
  const int strip = wv & 3;          // col strip (16 cols)
  const int quart = wv >> 2;         // edge quarter (32 edges)
  const int bt    = blockIdx.x;
  const int mrow  = lane & 15;
  const int g0    = (lane >> 4) << 2;

  // stage xT[i][r] (r in [0,128)); clamp phantom tile, validity handled via srcs
  for (int t = tid; t < 48 * TEB; t += 1024) {
    const int i = t >> 7, r = t & 127;
    int t64 = 2 * bt + (r >> 6); if (t64 >= NTILES) t64 = NTILES - 1;
    UN[t] = xTg[(size_t)t64 * 3072 + i * 64 + (r & 63)];
  }
  for (int t = tid; t < TEB * 4; t += 1024) {
    const int r = t >> 2;
    int t64 = 2 * bt + (r >> 6); if (t64 >= NTILES) t64 = NTILES - 1;
    shsS[t] = shsg[(size_t)t64 * 256 + (r & 63) * 4 + (t & 3)];
  }
  if (tid < TEB) {
    const int gi = bt * TEB + tid;
    int t64 = 2 * bt + (tid >> 6); if (t64 >= NTILES) t64 = NTILES - 1;
    srcsS[tid] = (gi < N_EDGE) ? srcsg[(size_t)t64 * 64 + (tid & 63)] : -1;
  }

  // hoist aF for this wave's 32-edge quarter (2 row-groups of 16)
  int t64a = 2 * bt + (quart >> 1); if (t64a >= NTILES) t64a = NTILES - 1;
  const short* hb = Hg + (size_t)t64a * 10240 + lane * 8;
  bf8 aF[2][5];
  #pragma unroll
  for (int mt = 0; mt < 2; ++mt)
    #pragma unroll
    for (int ks = 0; ks < 5; ++ks) {
      aF[mt][ks] = *(const bf8*)(hb + (((quart & 1) * 2 + mt) * 5 + ks) * 512);
      asm volatile("" : "+v"(aF[mt][ks]));
    }
  __syncthreads();  // xT staged

  f32x4 oacc[2];
  oacc[0] = (f32x4){0.f, 0.f, 0.f, 0.f};
  oacc[1] = (f32x4){0.f, 0.f, 0.f, 0.f};

  const short* gb = gfrag + strip * 2560 + lane * 8;
  auto loadB = [&](bf8 (&BF)[5], int i) {
    const short* p = gb + i * 10240;
    #pragma unroll
    for (int ks = 0; ks < 5; ++ks) BF[ks] = *(const bf8*)(p + ks * 512);
  };
  auto compute = [&](const bf8 (&BF)[5], int i) {
    #pragma unroll
    for (int mt = 0; mt < 2; ++mt) {
      f32x4 wi = {0.f, 0.f, 0.f, 0.f};
      #pragma unroll
      for (int ks = 0; ks < 5; ++ks)
        wi = __builtin_amdgcn_mfma_f32_16x16x32_bf16(aF[mt][ks], BF[ks], wi, 0, 0, 0);
      const float4 xs = *(const float4*)&UN[i * TEB + quart * 32 + mt * 16 + g0];
      oacc[mt][0] += xs.x * wi[0];
      oacc[mt][1] += xs.y * wi[1];
      oacc[mt][2] += xs.z * wi[2];
      oacc[mt][3] += xs.w * wi[3];
    }
  };

  // depth-2 pipeline; the 4 quarters of each strip issue identical loads -> L1 merge
  bf8 bA[5], bB[5];
  loadB(bA, 0);
  for (int i = 0; i < NS_; i += 2) {
    loadB(bB, i + 1);
    compute(bA, i);
    loadB(bA, (i + 2 < NS_) ? i + 2 : NS_ - 1);
    compute(bB, i + 1);
  }
  __syncthreads();  // all xs reads done -> safe to overwrite UN as O tile

  // ---- epilogue: scale into LDS O tile ----
  {
    const float nrm = 0.14433756729740643f;  // 1/sqrt(48)
    const int col = strip * 16 + mrow;
    #pragma unroll
    for (int mt = 0; mt < 2; ++mt) {
      #pragma unroll
      for (int r = 0; r < 4; ++r) {
        const int row = quart * 32 + mt * 16 + g0 + r;
        const float v = oacc[mt][r] * nrm;
        if (col < NS_) {
          UN[row * 80 + col] = v * shsS[row * 4 + 0];
        } else if (col < OUTC) {
          const int kp = col - NS_;
          UN[row * 80 + NS_ + kp * 3 + 0] = v * shsS[row * 4 + 1];
          UN[row * 80 + NS_ + kp * 3 + 1] = v * shsS[row * 4 + 2];
          UN[row * 80 + NS_ + kp * 3 + 2] = v * shsS[row * 4 + 3];
        }
      }
    }
  }
  __syncthreads();

  // run detection over 128 sorted srcs (waves 0 and 1)
  if (tid < TEB) {
    const int s = srcsS[tid];
    const bool valid = s >= 0;
    const bool head = valid && (tid == 0 || srcsS[tid - 1] != s);
    const unsigned long long hm = __ballot(head);
    const unsigned long long vm = __ballot(valid);
    if ((tid & 63) == 0) { hmaskSh[tid >> 6] = hm; vmaskSh[tid >> 6] = vm; }
  }
  __syncthreads();
  if (tid < TEB) {
    const int s = srcsS[tid];
    const bool valid = s >= 0;
    const bool head = valid && (tid == 0 || srcsS[tid - 1] != s);
    const int w = tid >> 6, l = tid & 63;
    const int rank = __popcll(hmaskSh[w] & ((1ull << l) - 1ull)) +
                     (w ? __popcll(hmaskSh[0]) : 0);
    if (head) { runStart[rank] = tid; runSrc[rank] = s; }
    if (tid == 0) {
      const int nR = __popcll(hmaskSh[0]) + __popcll(hmaskSh[1]);
      nRunsSh = nR;
      runStart[nR] = __popcll(vmaskSh[0]) + __popcll(vmaskSh[1]);  // valid rows = prefix
    }
  }
  __syncthreads();

  {
    const int nR = nRunsSh;
    for (int t = tid; t < nR * ODIM; t += 1024) {
      const int k = t / ODIM, c = t - k * ODIM;
      const int rs = runStart[k], re = runStart[k + 1];
      float s = 0.f;
      for (int r = rs; r < re; ++r) s += UN[r * 80 + c];
      atomicAdd(&out[(size_t)runSrc[k] * ODIM + c], s);
    }
  }
}

// ================= FALLBACK: fused kernel (used when ws_size is too small) =================
__global__ __launch_bounds__(256, 3) void fused_edge(
    const float* __restrict__ node_attr, const int* __restrict__ eidx,
    const float* __restrict__ edge_attr, const float* __restrict__ edge_sh,
    const float* __restrict__ fc1_b, const int* __restrict__ sortedE,
    const short* __restrict__ gfrag, const short* __restrict__ fc1frag,
    float* __restrict__ out)
{
  __shared__ short EA[TILE * LDE];
  __shared__ float xT[NS_ * TILE];
  __shared__ float shs[TILE * 4];
  __shared__ int   srcs[TILE];
  __shared__ int   runStart[TILE + 1], runSrc[TILE];
  __shared__ int   nRunsSh;

  const int tid  = threadIdx.x;
  const int lane = tid & 63;
  const int wv   = tid >> 6;
  const int base = blockIdx.x * TILE;

  for (int t = tid; t < TILE * 16; t += 256) {
    int r = t >> 4, c = t & 15;
    EA[r * LDE + HID + c] = 0;
  }
  {
    const int el = tid >> 2, part = tid & 3;
    const int gi = base + el;
    const bool ev = gi < N_EDGE;
    const int e  = ev ? sortedE[gi] : 0;
    const int es = ev ? eidx[e] : 0;
    const int ed = ev ? eidx[N_EDGE + e] : 0;
    if (part == 0) {
      srcs[el] = ev ? es : -1;
      #pragma unroll
      for (int c = 0; c < 4; ++c) shs[el * 4 + c] = ev ? edge_sh[(size_t)e * 9 + c] : 0.f;
    }
    const float4* pa = (const float4*)(edge_attr + (size_t)e * NS_);
    const float4* ps = (const float4*)(node_attr + (size_t)es * NS_);
    const float4* pd = (const float4*)(node_attr + (size_t)ed * NS_);
    const float4 z4 = make_float4(0.f, 0.f, 0.f, 0.f);
    #pragma unroll
    for (int q = 0; q < 3; ++q) {
      const int c0 = part * 12 + q * 4;
      float4 va = ev ? pa[part * 3 + q] : z4;
      float4 vs = ev ? ps[part * 3 + q] : z4;
      float4 vd = ev ? pd[part * 3 + q] : z4;
      *(uint2*)&EA[el * LDE + c0]           = make_uint2(pk2(va.x, va.y), pk2(va.z, va.w));
      *(uint2*)&EA[el * LDE + NS_ + c0]     = make_uint2(pk2(vs.x, vs.y), pk2(vs.z, vs.w));
      *(uint2*)&EA[el * LDE + 2 * NS_ + c0] = make_uint2(pk2(vd.x, vd.y), pk2(vd.z, vd.w));
      xT[(c0 + 0) * TILE + el] = vd.x;
      xT[(c0 + 1) * TILE + el] = vd.y;
      xT[(c0 + 2) * TILE + el] = vd.z;
      xT[(c0 + 3) * TILE + el] = vd.w;
    }
  }
  __syncthreads();
  {
    const int mrow = lane & 15;
    const int koff = (lane >> 4) << 3;
    bf8 aF[5];
    #pragma unroll
    for (int ks = 0; ks < 5; ++ks)
      aF[ks] = *(const bf8*)&EA[(wv * 16 + mrow) * LDE + ks * 32 + koff];
    #pragma unroll
    for (int nt = 0; nt < 9; ++nt) {
      f32x4 acc = {0.f, 0.f, 0.f, 0.f};
      #pragma unroll
      for (int ks = 0; ks < 5; ++ks) {
        bf8 bF = *(const bf8*)&fc1frag[((nt * 5 + ks) * 64 + lane) * 8];
        acc = __builtin_amdgcn_mfma_f32_16x16x32_bf16(aF[ks], bF, acc, 0, 0, 0);
      }
      const int col = nt * 16 + mrow;
      const float bb = fc1_b[col];
      #pragma unroll
      for (int r = 0; r < 4; ++r) {
        float h = acc[r] + bb;
        h = h > 0.f ? h : 0.f;
        EA[(wv * 16 + ((lane >> 4) << 2) + r) * LDE + col] = f2bf(h);
      }
    }
    if (lane < 16) EA[(wv * 16 + lane) * LDE + HID] = (short)0x3F80;
  }
  __syncthreads();
  {
    const int mrow = lane & 15;
    const int koff = (lane >> 4) << 3;
    const int g0 = (lane >> 4) << 2;

    f32x4 oacc[4];
    #pragma unroll
    for (int mt = 0; mt < 4; ++mt) oacc[mt] = (f32x4){0.f, 0.f, 0.f, 0.f};

    bf8 aF[4][5];
    #pragma unroll
    for (int mt = 0; mt < 4; ++mt)
      #pragma unroll
      for (int ks = 0; ks < 5; ++ks) {
        aF[mt][ks] = *(const bf8*)&EA[(mt * 16 + mrow) * LDE + ks * 32 + koff];
        asm volatile("" : "+v"(aF[mt][ks]));
      }
    __syncthreads();

    const short* gb = gfrag + wv * 2560 + lane * 8;
    auto loadB = [&](bf8 (&BF)[5], int i) {
      const short* p = gb + i * 10240;
      #pragma unroll
      for (int ks = 0; ks < 5; ++ks) BF[ks] = *(const bf8*)(p + ks * 512);
    };
    auto compute = [&](const bf8 (&BF)[5], int i) {
      #pragma unroll
      for (int mt = 0; mt < 4; ++mt) {
        f32x4 wi = {0.f, 0.f, 0.f, 0.f};
        #pragma unroll
        for (int ks = 0; ks < 5; ++ks)
          wi = __builtin_amdgcn_mfma_f32_16x16x32_bf16(aF[mt][ks], BF[ks], wi, 0, 0, 0);
        const float4 xs = *(const float4*)&xT[i * TILE + mt * 16 + g0];
        oacc[mt][0] += xs.x * wi[0];
        oacc[mt][1] += xs.y * wi[1];
        oacc[mt][2] += xs.z * wi[2];
        oacc[mt][3] += xs.w * wi[3];
      }
    };
    bf8 bA[5], bB[5];
    loadB(bA, 0);
    for (int i = 0; i < NS_; i += 2) {
      loadB(bB, i + 1);
      compute(bA, i);
      loadB(bA, (i + 2 < NS_) ? i + 2 : NS_ - 1);
      compute(bB, i + 1);
    }

    float* O = (float*)EA;
    const float nrm = 0.14433756729740643f;
    const int col = wv * 16 + mrow;
    #pragma unroll
    for (int mt = 0; mt < 4; ++mt) {
      #pragma unroll
      for (int r = 0; r < 4; ++r) {
        const int row = mt * 16 + g0 + r;
        const float v = oacc[mt][r] * nrm;
        if (col < NS_) {
          O[row * 80 + col] = v * shs[row * 4 + 0];
        } else if (col < OUTC) {
          const int kp = col - NS_;
          O[row * 80 + NS_ + kp * 3 + 0] = v * shs[row * 4 + 1];
          O[row * 80 + NS_ + kp * 3 + 1] = v * shs[row * 4 + 2];
          O[row * 80 + NS_ + kp * 3 + 2] = v * shs[row * 4 + 3];
        }
      }
    }
  }
  __syncthreads();
  if (tid < 64) {
    const int s = srcs[tid];
    const bool valid = s >= 0;
    const bool head = valid && (tid == 0 || srcs[tid - 1] != s);
    const unsigned long long hm = __ballot(head);
    const unsigned long long vm = __ballot(valid);
    const int rank = __popcll(hm & ((1ull << tid) - 1ull));
    if (head) { runStart[rank] = tid; runSrc[rank] = s; }
    if (tid == 0) {
      const int nR = __popcll(hm);
      nRunsSh = nR;
      runStart[nR] = __popcll(vm);
    }
  }
  __syncthreads();
  {
    const float* O = (const float*)EA;
    const int nR = nRunsSh;
    for (int t = tid; t < nR * ODIM; t += 256) {
      const int k = t / ODIM, c = t - k * ODIM;
      const int rs = runStart[k], re = runStart[k + 1];
      float s = 0.f;
      for (int r = rs; r < re; ++r) s += O[r * 80 + c];
      atomicAdd(&out[(size_t)runSrc[k] * ODIM + c], s);
    }
  }
}

__global__ void finalize(float* __restrict__ out, const int* __restrict__ cnt) {
  int idx = blockIdx.x * 256 + threadIdx.x;
  if (idx >= N_NODE * ODIM) return;
  int n = idx / ODIM;
  out[idx] = out[idx] / fmaxf((float)cnt[n], 1.f);
}

extern "C" void kernel_launch(void* const* d_in, const int* in_sizes, int n_in,
                              void* d_out, int out_size, void* d_ws, size_t ws_size,
                              hipStream_t stream) {
  (void)in_sizes; (void)n_in; (void)out_size;
  const float* node_attr = (const float*)d_in[0];
  const int*   eidx      = (const int*)d_in[1];
  const float* edge_attr = (const float*)d_in[2];
  const float* edge_sh   = (const float*)d_in[3];
  const float* fc1_w     = (const float*)d_in[4];
  const float* fc1_b     = (const float*)d_in[5];
  const float* fc2_w     = (const float*)d_in[6];
  const float* fc2_b     = (const float*)d_in[7];
  float* out = (float*)d_out;

  char* ws = (char*)d_ws;
  short* gfrag   = (short*)(ws);                    // 983040 B
  short* fc1frag = (short*)(ws + 983040);           // 46080 B
  int*   cnt     = (int*)(ws + 1029120);            // 80000 B
  int*   locexc  = (int*)(ws + 1109120);            // 80000 B
  int*   cursor  = (int*)(ws + 1189120);            // 80000 B
  int*   blksum  = (int*)(ws + 1269120);            // 512 B
  int*   blkoff  = (int*)(ws + 1269632);            // 512 B
  int*   sortedE = (int*)(ws + 1270144);            // 400000 B
  int*   srcsg   = (int*)(ws + 1670144);            // 400128 B
  float* shsg    = (float*)(ws + 2070272);          // 1600512 B
  float* xTg     = (float*)(ws + 3670784);          // 19206144 B
  short* Hg      = (short*)(ws + 22876928);         // 32010240 B -> end 54887168
  const size_t NEED_SPLIT = 54887168;

  hipMemsetAsync(out, 0, (size_t)N_NODE * ODIM * sizeof(float), stream);
  hipMemsetAsync(cnt, 0, N_NODE * sizeof(int), stream);
  hipMemsetAsync(cursor, 0, N_NODE * sizeof(int), stream);

  prep_fc1<<<(9 * 5 * 512 + 255) / 256, 256, 0, stream>>>(fc1_w, fc1frag);
  prep_g<<<(48 * 4 * 5 * 512 + 255) / 256, 256, 0, stream>>>(fc2_w, fc2_b, gfrag);

  k_hist<<<(N_EDGE + 255) / 256, 256, 0, stream>>>(eidx, cnt);
  k_scan1<<<(N_NODE + 255) / 256, 256, 0, stream>>>(cnt, locexc, blksum);
  k_scan2<<<1, 128, 0, stream>>>(blksum, blkoff);
  k_scatter<<<(N_EDGE + 255) / 256, 256, 0, stream>>>(eidx, locexc, blkoff, cursor, sortedE);

  if (ws_size >= NEED_SPLIT) {
    gather_fc1<<<NTILES, 256, 0, stream>>>(
        node_attr, eidx, edge_attr, edge_sh, fc1_b, sortedE, fc1frag,
        Hg, xTg, shsg, srcsg);
    tp_scatter<<<NB2, 1024, 0, stream>>>(gfrag, Hg, xTg, shsg, srcsg, out);
  } else {
    fused_edge<<<NTILES, 256, 0, stream>>>(
        node_attr, eidx, edge_attr, edge_sh, fc1_b, sortedE, gfrag, fc1frag, out);
  }

  finalize<<<(N_NODE * ODIM + 255) / 256, 256, 0, stream>>>(out, cnt);
}

// Round 9
// 170.308 us; speedup vs baseline: 1.3871x; 1.3871x over previous
//
#include <hip/hip_runtime.h>
#include <hip/hip_bf16.h>

#define NS_    48
#define NV_    10
#define N_NODE 20000
#define N_EDGE 100000
#define HID    144     // 3*NS
#define OUTC   58      // 48 + 10
#define ODIM   78      // 48 + 30
#define TILE   64
#define NTILES 1563    // ceil(100000/64)
#define LDE    160     // padded K (144->160), LDS row stride (bf16 elems)
#define WNUM   2784

typedef __attribute__((ext_vector_type(8))) short bf8;
typedef __attribute__((ext_vector_type(4))) float f32x4;

__device__ __forceinline__ short f2bf(float x) {
  __hip_bfloat16 h = __float2bfloat16(x);
  union { __hip_bfloat16 b; short s; } u; u.b = h; return u.s;
}
__device__ __forceinline__ unsigned pk2(float a, float b) {
  return (unsigned)(unsigned short)f2bf(a) | ((unsigned)(unsigned short)f2bf(b) << 16);
}

// ---------------- prep: pack B operands into MFMA fragment order ----------------
__global__ void prep_fc1(const float* __restrict__ w, short* __restrict__ dst) {
  int idx = blockIdx.x * 256 + threadIdx.x;
  if (idx >= 9 * 5 * 512) return;
  int j = idx & 7, l = (idx >> 3) & 63, t = idx >> 9;
  int ks = t % 5, nt = t / 5;
  int k = ks * 32 + ((l >> 4) << 3) + j;
  int n = nt * 16 + (l & 15);
  dst[idx] = f2bf(k < HID ? w[k * HID + n] : 0.f);
}

// G frags: [i 48][strip 4][ks 5][lane][j]; row k==144 carries fc2_b (pairs with H col144==1)
__global__ void prep_g(const float* __restrict__ w, const float* __restrict__ b,
                       short* __restrict__ dst) {
  int idx = blockIdx.x * 256 + threadIdx.x;
  if (idx >= 48 * 4 * 5 * 512) return;
  int j = idx & 7, l = (idx >> 3) & 63, t = idx >> 9;
  int ks = t % 5, u = t / 5;
  int strip = u & 3, i = u >> 2;
  int k = ks * 32 + ((l >> 4) << 3) + j;
  int c = strip * 16 + (l & 15);
  float v = 0.f;
  if (c < OUTC) {
    if (k < HID)
      v = (c < NS_) ? w[k * WNUM + i * NS_ + c]
                    : w[k * WNUM + NS_ * NS_ + i * NV_ + (c - NS_)];
    else if (k == HID)
      v = (c < NS_) ? b[i * NS_ + c]
                    : b[NS_ * NS_ + i * NV_ + (c - NS_)];
  }
  dst[idx] = f2bf(v);
}

// ---------------- CSR build: counting sort of edges by src ----------------
__global__ void k_hist(const int* __restrict__ eidx, int* __restrict__ cnt) {
  int e = blockIdx.x * 256 + threadIdx.x;
  if (e < N_EDGE) atomicAdd(&cnt[eidx[e]], 1);
}

__global__ void k_scan1(const int* __restrict__ cnt, int* __restrict__ locexc,
                        int* __restrict__ blksum) {
  __shared__ int sh[256];
  int g = blockIdx.x * 256 + threadIdx.x;
  int v = (g < N_NODE) ? cnt[g] : 0;
  sh[threadIdx.x] = v;
  __syncthreads();
  for (int d = 1; d < 256; d <<= 1) {
    int t = (threadIdx.x >= d) ? sh[threadIdx.x - d] : 0;
    __syncthreads();
    sh[threadIdx.x] += t;
    __syncthreads();
  }
  if (g < N_NODE) locexc[g] = sh[threadIdx.x] - v;
  if (threadIdx.x == 255) blksum[blockIdx.x] = sh[255];
}

__global__ void k_scan2(const int* __restrict__ blksum, int* __restrict__ blkoff) {
  __shared__ int sh[128];
  int t = threadIdx.x;
  int v = (t < 79) ? blksum[t] : 0;
  sh[t] = v;
  __syncthreads();
  for (int d = 1; d < 128; d <<= 1) {
    int x = (t >= d) ? sh[t - d] : 0;
    __syncthreads();
    sh[t] += x;
    __syncthreads();
  }
  if (t < 79) blkoff[t] = sh[t] - v;
}

__global__ void k_scatter(const int* __restrict__ eidx, const int* __restrict__ locexc,
                          const int* __restrict__ blkoff, int* __restrict__ cursor,
                          int* __restrict__ sortedE) {
  int e = blockIdx.x * 256 + threadIdx.x;
  if (e >= N_EDGE) return;
  int s = eidx[e];
  int base = blkoff[s >> 8] + locexc[s];
  int r = atomicAdd(&cursor[s], 1);
  sortedE[base + r] = e;
}

// ---------------- main fused kernel: 64 sorted edges per WG, 4 waves ----------------
// R4 structure (best measured: 147 us) + i-loop rotation by blockIdx to spread
// concurrent blocks across 48 different gfrag slices (L2 hot-bank fix).
__global__ __launch_bounds__(256, 3) void fused_edge(
    const float* __restrict__ node_attr, const int* __restrict__ eidx,
    const float* __restrict__ edge_attr, const float* __restrict__ edge_sh,
    const float* __restrict__ fc1_b, const int* __restrict__ sortedE,
    const short* __restrict__ gfrag, const short* __restrict__ fc1frag,
    float* __restrict__ out)
{
  __shared__ short EA[TILE * LDE];   // ea tile -> H tile -> O tile (float[64][80])
  __shared__ float xT[NS_ * TILE];   // x transposed: xT[i][e]
  __shared__ float shs[TILE * 4];    // edge_sh cols 0..3
  __shared__ int   srcs[TILE];       // sorted srcs (-1 for invalid rows)
  __shared__ int   runStart[TILE + 1], runSrc[TILE];
  __shared__ int   nRunsSh;

  const int tid  = threadIdx.x;
  const int lane = tid & 63;
  const int wv   = tid >> 6;
  const int base = blockIdx.x * TILE;

  // zero K-pad cols 144..159
  for (int t = tid; t < TILE * 16; t += 256) {
    int r = t >> 4, c = t & 15;
    EA[r * LDE + HID + c] = 0;
  }

  // ---- gather (src-sorted edge ids): 4 threads per edge, 12 cols each ----
  {
    const int el = tid >> 2, part = tid & 3;
    const int gi = base + el;
    const bool ev = gi < N_EDGE;
    const int e  = ev ? sortedE[gi] : 0;
    const int es = ev ? eidx[e] : 0;
    const int ed = ev ? eidx[N_EDGE + e] : 0;
    if (part == 0) {
      srcs[el] = ev ? es : -1;
      #pragma unroll
      for (int c = 0; c < 4; ++c) shs[el * 4 + c] = ev ? edge_sh[(size_t)e * 9 + c] : 0.f;
    }
    const float4* pa = (const float4*)(edge_attr + (size_t)e * NS_);
    const float4* ps = (const float4*)(node_attr + (size_t)es * NS_);
    const float4* pd = (const float4*)(node_attr + (size_t)ed * NS_);
    const float4 z4 = make_float4(0.f, 0.f, 0.f, 0.f);
    #pragma unroll
    for (int q = 0; q < 3; ++q) {
      const int c0 = part * 12 + q * 4;
      float4 va = ev ? pa[part * 3 + q] : z4;
      float4 vs = ev ? ps[part * 3 + q] : z4;
      float4 vd = ev ? pd[part * 3 + q] : z4;
      *(uint2*)&EA[el * LDE + c0]           = make_uint2(pk2(va.x, va.y), pk2(va.z, va.w));
      *(uint2*)&EA[el * LDE + NS_ + c0]     = make_uint2(pk2(vs.x, vs.y), pk2(vs.z, vs.w));
      *(uint2*)&EA[el * LDE + 2 * NS_ + c0] = make_uint2(pk2(vd.x, vd.y), pk2(vd.z, vd.w));
      xT[(c0 + 0) * TILE + el] = vd.x;
      xT[(c0 + 1) * TILE + el] = vd.y;
      xT[(c0 + 2) * TILE + el] = vd.z;
      xT[(c0 + 3) * TILE + el] = vd.w;
    }
  }
  __syncthreads();

  // ---- fc1: wave wv computes H rows [wv*16, wv*16+16); H overwrites EA in place ----
  {
    const int mrow = lane & 15;
    const int koff = (lane >> 4) << 3;
    bf8 aF[5];
    #pragma unroll
    for (int ks = 0; ks < 5; ++ks)
      aF[ks] = *(const bf8*)&EA[(wv * 16 + mrow) * LDE + ks * 32 + koff];
    #pragma unroll
    for (int nt = 0; nt < 9; ++nt) {
      f32x4 acc = {0.f, 0.f, 0.f, 0.f};
      #pragma unroll
      for (int ks = 0; ks < 5; ++ks) {
        bf8 bF = *(const bf8*)&fc1frag[((nt * 5 + ks) * 64 + lane) * 8];
        acc = __builtin_amdgcn_mfma_f32_16x16x32_bf16(aF[ks], bF, acc, 0, 0, 0);
      }
      const int col = nt * 16 + mrow;
      const float bb = fc1_b[col];
      #pragma unroll
      for (int r = 0; r < 4; ++r) {
        float h = acc[r] + bb;
        h = h > 0.f ? h : 0.f;
        EA[(wv * 16 + ((lane >> 4) << 2) + r) * LDE + col] = f2bf(h);
      }
    }
    if (lane < 16) EA[(wv * 16 + lane) * LDE + HID] = (short)0x3F80;  // 1.0 col for bias
  }
  __syncthreads();

  // ---- phase 2: wave wv owns output cols [wv*16, wv*16+16) for all 64 edges ----
  {
    const int mrow = lane & 15;
    const int koff = (lane >> 4) << 3;
    const int g0 = (lane >> 4) << 2;

    f32x4 oacc[4];
    #pragma unroll
    for (int mt = 0; mt < 4; ++mt) oacc[mt] = (f32x4){0.f, 0.f, 0.f, 0.f};

    // hoist A-fragments of H (reused 48x); pin against rematerialization
    bf8 aF[4][5];
    #pragma unroll
    for (int mt = 0; mt < 4; ++mt)
      #pragma unroll
      for (int ks = 0; ks < 5; ++ks) {
        aF[mt][ks] = *(const bf8*)&EA[(mt * 16 + mrow) * LDE + ks * 32 + koff];
        asm volatile("" : "+v"(aF[mt][ks]));
      }
    __syncthreads();  // all waves done reading EA -> safe to alias as O later

    const short* gb = gfrag + wv * 2560 + lane * 8;
    auto loadB = [&](bf8 (&BF)[5], int i) {
      const short* p = gb + i * 10240;
      #pragma unroll
      for (int ks = 0; ks < 5; ++ks) BF[ks] = *(const bf8*)(p + ks * 512);
    };
    auto compute = [&](const bf8 (&BF)[5], int i) {
      #pragma unroll
      for (int mt = 0; mt < 4; ++mt) {
        f32x4 wi = {0.f, 0.f, 0.f, 0.f};
        #pragma unroll
        for (int ks = 0; ks < 5; ++ks)
          wi = __builtin_amdgcn_mfma_f32_16x16x32_bf16(aF[mt][ks], BF[ks], wi, 0, 0, 0);
        const float4 xs = *(const float4*)&xT[i * TILE + mt * 16 + g0];
        oacc[mt][0] += xs.x * wi[0];
        oacc[mt][1] += xs.y * wi[1];
        oacc[mt][2] += xs.z * wi[2];
        oacc[mt][3] += xs.w * wi[3];
      }
    };

    // i-loop rotated per block: concurrent blocks read DIFFERENT G_i slices,
    // spreading the broadcast stream across L2 banks/channels.
    const int roff = (int)(blockIdx.x % (unsigned)NS_);
    auto rot = [&](int i) { int r = i + roff; return (r >= NS_) ? r - NS_ : r; };

    bf8 bA[5], bB[5];
    loadB(bA, rot(0));
    for (int i = 0; i < NS_; i += 2) {
      loadB(bB, rot(i + 1));
      compute(bA, rot(i));
      loadB(bA, rot((i + 2 < NS_) ? i + 2 : NS_ - 1));
      compute(bB, rot(i + 1));
    }

    // ---- epilogue: scale into LDS O tile (aliases EA), run-reduce, few atomics ----
    float* O = (float*)EA;  // [64][80] f32 = 20480 B, exactly EA's size
    const float nrm = 0.14433756729740643f;  // 1/sqrt(48)
    const int col = wv * 16 + mrow;
    #pragma unroll
    for (int mt = 0; mt < 4; ++mt) {
      #pragma unroll
      for (int r = 0; r < 4; ++r) {
        const int row = mt * 16 + g0 + r;
        const float v = oacc[mt][r] * nrm;
        if (col < NS_) {
          O[row * 80 + col] = v * shs[row * 4 + 0];
        } else if (col < OUTC) {
          const int kp = col - NS_;
          O[row * 80 + NS_ + kp * 3 + 0] = v * shs[row * 4 + 1];
          O[row * 80 + NS_ + kp * 3 + 1] = v * shs[row * 4 + 2];
          O[row * 80 + NS_ + kp * 3 + 2] = v * shs[row * 4 + 3];
        }
      }
    }
  }
  __syncthreads();

  // run detection over sorted srcs (wave 0)
  if (tid < 64) {
    const int s = srcs[tid];
    const bool valid = s >= 0;
    const bool head = valid && (tid == 0 || srcs[tid - 1] != s);
    const unsigned long long hm = __ballot(head);
    const unsigned long long vm = __ballot(valid);
    const int rank = __popcll(hm & ((1ull << tid) - 1ull));
    if (head) { runStart[rank] = tid; runSrc[rank] = s; }
    if (tid == 0) {
      const int nR = __popcll(hm);
      nRunsSh = nR;
      runStart[nR] = __popcll(vm);  // valid rows form a prefix
    }
  }
  __syncthreads();

  {
    const float* O = (const float*)EA;
    const int nR = nRunsSh;
    for (int t = tid; t < nR * ODIM; t += 256) {
      const int k = t / ODIM, c = t - k * ODIM;
      const int rs = runStart[k], re = runStart[k + 1];
      float s = 0.f;
      for (int r = rs; r < re; ++r) s += O[r * 80 + c];
      atomicAdd(&out[(size_t)runSrc[k] * ODIM + c], s);
    }
  }
}

__global__ void finalize(float* __restrict__ out, const int* __restrict__ cnt) {
  int idx = blockIdx.x * 256 + threadIdx.x;
  if (idx >= N_NODE * ODIM) return;
  int n = idx / ODIM;
  out[idx] = out[idx] / fmaxf((float)cnt[n], 1.f);
}

extern "C" void kernel_launch(void* const* d_in, const int* in_sizes, int n_in,
                              void* d_out, int out_size, void* d_ws, size_t ws_size,
                              hipStream_t stream) {
  (void)in_sizes; (void)n_in; (void)out_size; (void)ws_size;
  const float* node_attr = (const float*)d_in[0];
  const int*   eidx      = (const int*)d_in[1];
  const float* edge_attr = (const float*)d_in[2];
  const float* edge_sh   = (const float*)d_in[3];
  const float* fc1_w     = (const float*)d_in[4];
  const float* fc1_b     = (const float*)d_in[5];
  const float* fc2_w     = (const float*)d_in[6];
  const float* fc2_b     = (const float*)d_in[7];
  float* out = (float*)d_out;

  char* ws = (char*)d_ws;
  short* gfrag   = (short*)(ws);                    // 983040 B
  short* fc1frag = (short*)(ws + 983040);           // 46080 B
  int*   cnt     = (int*)(ws + 1029120);            // 80000 B
  int*   locexc  = (int*)(ws + 1109120);            // 80000 B
  int*   cursor  = (int*)(ws + 1189120);            // 80000 B
  int*   blksum  = (int*)(ws + 1269120);            // 512 B
  int*   blkoff  = (int*)(ws + 1269632);            // 512 B
  int*   sortedE = (int*)(ws + 1270144);            // 400000 B

  hipMemsetAsync(out, 0, (size_t)N_NODE * ODIM * sizeof(float), stream);
  hipMemsetAsync(cnt, 0, N_NODE * sizeof(int), stream);
  hipMemsetAsync(cursor, 0, N_NODE * sizeof(int), stream);

  prep_fc1<<<(9 * 5 * 512 + 255) / 256, 256, 0, stream>>>(fc1_w, fc1frag);
  prep_g<<<(48 * 4 * 5 * 512 + 255) / 256, 256, 0, stream>>>(fc2_w, fc2_b, gfrag);

  k_hist<<<(N_EDGE + 255) / 256, 256, 0, stream>>>(eidx, cnt);
  k_scan1<<<(N_NODE + 255) / 256, 256, 0, stream>>>(cnt, locexc, blksum);
  k_scan2<<<1, 128, 0, stream>>>(blksum, blkoff);
  k_scatter<<<(N_EDGE + 255) / 256, 256, 0, stream>>>(eidx, locexc, blkoff, cursor, sortedE);

  fused_edge<<<NTILES, 256, 0, stream>>>(
      node_attr, eidx, edge_attr, edge_sh, fc1_b, sortedE, gfrag, fc1frag, out);

  finalize<<<(N_NODE * ODIM + 255) / 256, 256, 0, stream>>>(out, cnt);
}